// Round 7
// baseline (461.559 us; speedup 1.0000x reference)
//
#include <hip/hip_runtime.h>
#include <hip/hip_fp16.h>
#include <math.h>

// ---------------------------------------------------------------------------
// DevignLite: 3-layer GCN + mean/max pool + MLP head.  N=100000, E=1.6M,
// D=64, G=256.
// Round 7:
//  - Aggregate: 8 dst nodes per wave; lane=(node n8, 16B-offset o).  Each
//    node's 8 lanes hold its full row -> NO epilogue shuffle tree, prologue
//    amortized 8x.  Inner trip = wave-max degree (3 shfl), masked lanes
//    issue but don't fetch.  (R6 lesson: per-list chunk sort can't create
//    cross-wave locality -> reverted; FETCH unchanged at 158MB.)
//  - Matmul: float2 ext-vector accs + __builtin_elementwise_fma ->
//    v_pk_fma_f32, halves VALU issue (was ~4096 scalar FMA/wave).
// ---------------------------------------------------------------------------

#define BKT_LOG 9
#define BKT (1 << BKT_LOG)   // 512 nodes per coarse bucket
#define CHUNK 2048           // edges per k_part block (8 per thread)

typedef float v2f __attribute__((ext_vector_type(2)));

__global__ void k_zero(float* p, long n) {
  long i = (long)blockIdx.x * blockDim.x + threadIdx.x;
  if (i < n) p[i] = 0.0f;
}

// coarse histogram of dst >> BKT_LOG
__global__ __launch_bounds__(256) void k_chist(const int* __restrict__ dst,
                                               int* __restrict__ chist, int E, int B) {
  __shared__ int h[256];
  h[threadIdx.x] = 0;
  __syncthreads();
  for (long e = (long)blockIdx.x * blockDim.x + threadIdx.x; e < E;
       e += (long)gridDim.x * blockDim.x)
    atomicAdd(&h[dst[e] >> BKT_LOG], 1);
  __syncthreads();
  if (threadIdx.x < B && h[threadIdx.x]) atomicAdd(&chist[threadIdx.x], h[threadIdx.x]);
}

// exclusive scan of chist[B] -> cbase[B+1]; cursor copy -> gcur
__global__ __launch_bounds__(256) void k_cscan(const int* __restrict__ chist,
                                               int* __restrict__ cbase,
                                               int* __restrict__ gcur, int E, int B) {
  __shared__ int s[256];
  int v = (threadIdx.x < B) ? chist[threadIdx.x] : 0;
  s[threadIdx.x] = v;
  __syncthreads();
  for (int d = 1; d < 256; d <<= 1) {
    int t = (threadIdx.x >= (unsigned)d) ? s[threadIdx.x - d] : 0;
    __syncthreads();
    s[threadIdx.x] += t;
    __syncthreads();
  }
  if (threadIdx.x < B) {
    int ex = s[threadIdx.x] - v;
    cbase[threadIdx.x] = ex;
    gcur[threadIdx.x] = ex;
  }
  if (threadIdx.x == B) cbase[B] = E;
}

// partition pass: scatter (src,dst) pairs into coarse-bucket order.
// Block-exclusive contiguous slices -> single writer per cache line.
__global__ __launch_bounds__(256) void k_part(const int* __restrict__ src,
                                              const int* __restrict__ dst,
                                              int* __restrict__ gcur,
                                              int2* __restrict__ ebuf, int E, int B) {
  __shared__ int h[256], base[256], cur[256];
  long c0 = (long)blockIdx.x * CHUNK;
  int m = (int)min((long)CHUNK, (long)E - c0);
  int sreg[8], dreg[8];
  h[threadIdx.x] = 0;
  __syncthreads();
#pragma unroll
  for (int j = 0; j < 8; j++) {
    int idx = threadIdx.x + j * 256;
    if (idx < m) {
      sreg[j] = src[c0 + idx];
      dreg[j] = dst[c0 + idx];
      atomicAdd(&h[dreg[j] >> BKT_LOG], 1);
    }
  }
  __syncthreads();
  if (threadIdx.x < B && h[threadIdx.x])
    base[threadIdx.x] = atomicAdd(&gcur[threadIdx.x], h[threadIdx.x]);
  cur[threadIdx.x] = 0;
  __syncthreads();
#pragma unroll
  for (int j = 0; j < 8; j++) {
    int idx = threadIdx.x + j * 256;
    if (idx < m) {
      int k = dreg[j] >> BKT_LOG;
      int p = base[k] + atomicAdd(&cur[k], 1);
      ebuf[p] = make_int2(sreg[j], dreg[j]);
    }
  }
}

// per-bucket: node histogram + scan in LDS -> off/dinv, then place csrc.
__global__ __launch_bounds__(512) void k_bplace(const int2* __restrict__ ebuf,
                                                const int* __restrict__ cbase,
                                                int* __restrict__ off,
                                                int* __restrict__ csrc,
                                                float* __restrict__ dinv,
                                                int N, int E) {
  __shared__ int s[512];
  __shared__ int cur[512];
  int b = blockIdx.x, tid = threadIdx.x;
  int n0 = b << BKT_LOG;
  int nn = min(BKT, N - n0);
  int e0 = cbase[b], e1 = cbase[b + 1];
  s[tid] = 0;
  __syncthreads();
  for (int e = e0 + tid; e < e1; e += 512) atomicAdd(&s[ebuf[e].y - n0], 1);
  __syncthreads();
  int deg = s[tid];
  for (int d = 1; d < 512; d <<= 1) {
    int t = (tid >= d) ? s[tid - d] : 0;
    __syncthreads();
    s[tid] += t;
    __syncthreads();
  }
  int excl = s[tid] - deg;
  if (tid < nn) {
    off[n0 + tid] = e0 + excl;
    dinv[n0 + tid] = 1.0f / sqrtf((float)(1 + deg));
  }
  cur[tid] = excl;
  __syncthreads();
  for (int e = e0 + tid; e < e1; e += 512) {
    int2 p = ebuf[e];
    int pos = e0 + atomicAdd(&cur[p.y - n0], 1);
    csrc[pos] = p.x;
  }
  if (b == 0 && tid == 0) off[N] = E;
}

// ---------------------------------------------------------------------------
// Matmul, lane = row.  xw_h[row] = act(xin[row]) @ W * (256*dinv[row]), fp16.
// W via wave-uniform broadcast loads; 32 packed-f32 accumulators per lane.
// ---------------------------------------------------------------------------
template <bool EMB, bool ACT>
__global__ __launch_bounds__(256) void k_matmul(const float* __restrict__ xin,
                                                const int* __restrict__ tok,
                                                const float* __restrict__ emb,
                                                const float* __restrict__ W,
                                                const float* __restrict__ bprev,
                                                const float* __restrict__ dinv,
                                                __half2* __restrict__ xwh, int n) {
  long row = (long)blockIdx.x * 256 + threadIdx.x;
  if (row >= n) return;
  const float4* W4 = (const float4*)W;
  const float4* b4 = (const float4*)bprev;
  const float4* xr;
  if (EMB) xr = (const float4*)(emb + (size_t)tok[row] * 64);
  else     xr = (const float4*)(xin + (size_t)row * 64);
  v2f acc[32];
#pragma unroll
  for (int i = 0; i < 32; i++) acc[i] = (v2f)(0.f);

  for (int d4 = 0; d4 < 16; d4++) {
    float4 xv = xr[d4];
    if (ACT) {
      float4 bb = b4[d4];
      xv.x = fmaxf(xv.x + bb.x, 0.f);
      xv.y = fmaxf(xv.y + bb.y, 0.f);
      xv.z = fmaxf(xv.z + bb.z, 0.f);
      xv.w = fmaxf(xv.w + bb.w, 0.f);
    }
    const float xs[4] = {xv.x, xv.y, xv.z, xv.w};
#pragma unroll
    for (int r = 0; r < 4; r++) {
      const float4* wr = W4 + (size_t)(d4 * 4 + r) * 16;   // uniform address
      v2f x2 = {xs[r], xs[r]};
#pragma unroll
      for (int cb = 0; cb < 16; cb++) {
        float4 w = wr[cb];
        v2f w0 = {w.x, w.y}, w1 = {w.z, w.w};
        acc[cb * 2 + 0] = __builtin_elementwise_fma(x2, w0, acc[cb * 2 + 0]);
        acc[cb * 2 + 1] = __builtin_elementwise_fma(x2, w1, acc[cb * 2 + 1]);
      }
    }
  }
  float di = dinv[row] * 256.0f;       // fp16-range scale, undone in aggregate
  __half2 hh[32];
#pragma unroll
  for (int c = 0; c < 32; c++)
    hh[c] = __float22half2_rn(make_float2(acc[c].x * di, acc[c].y * di));
  uint4* dst = (uint4*)(xwh + (size_t)row * 32);
  const uint4* src = (const uint4*)hh;
#pragma unroll
  for (int k = 0; k < 8; k++) dst[k] = src[k];
}

// ---------------------------------------------------------------------------
// Aggregate: 8 dst nodes per wave.  lane = (n8, o): node t = wave*8+n8,
// o = 16B offset within the 128B fp16 row.  Each node's 8 lanes accumulate
// its full row in fp32 -> no reduction shuffles.  Inner trip = wave-max
// degree; masked lanes issue but don't fetch.
// agg[t] = (dinv[t]/256) * (xh[t] + sum_{s in in(t)} xh[s])   (fp32 out)
// ---------------------------------------------------------------------------
__global__ __launch_bounds__(256) void k_aggregate(const int* __restrict__ off,
                                                   const int* __restrict__ csrc,
                                                   const float* __restrict__ dinv,
                                                   const __half2* __restrict__ xh,
                                                   float* __restrict__ agg, int n) {
  int wave = (blockIdx.x * blockDim.x + threadIdx.x) >> 6;
  int lane = threadIdx.x & 63;
  int n8 = lane >> 3, o = lane & 7;
  int t = wave * 8 + n8;
  bool valid = t < n;
  int tc = valid ? t : n - 1;
  int e0 = off[tc], e1 = off[tc + 1];
  if (!valid) e1 = e0;
  const uint4* x4 = (const uint4*)xh;

  float acc[8];
  {  // self term
    uint4 v = x4[(size_t)tc * 8 + o];
    const __half2* hv = (const __half2*)&v;
#pragma unroll
    for (int k = 0; k < 4; k++) {
      float2 f = __half22float2(hv[k]);
      acc[2 * k] = f.x;
      acc[2 * k + 1] = f.y;
    }
  }

  // wave-max degree over the 8 node-subgroups (bits 3,4,5 of lane)
  int deg = e1 - e0;
  int mx = deg;
#pragma unroll
  for (int m = 8; m < 64; m <<= 1) mx = max(mx, __shfl_xor(mx, m));

  for (int r = 0; r < mx; r += 2) {
    int i0 = e0 + r, i1 = e0 + r + 1;
    int s0 = (i0 < e1) ? csrc[i0] : -1;   // 8-lane broadcast load
    int s1 = (i1 < e1) ? csrc[i1] : -1;
    uint4 v0, v1;
    if (s0 >= 0) v0 = x4[(size_t)s0 * 8 + o];
    if (s1 >= 0) v1 = x4[(size_t)s1 * 8 + o];
    if (s0 >= 0) {
      const __half2* hv = (const __half2*)&v0;
#pragma unroll
      for (int k = 0; k < 4; k++) {
        float2 f = __half22float2(hv[k]);
        acc[2 * k] += f.x;
        acc[2 * k + 1] += f.y;
      }
    }
    if (s1 >= 0) {
      const __half2* hv = (const __half2*)&v1;
#pragma unroll
      for (int k = 0; k < 4; k++) {
        float2 f = __half22float2(hv[k]);
        acc[2 * k] += f.x;
        acc[2 * k + 1] += f.y;
      }
    }
  }

  if (valid) {
    float sc = dinv[t] * (1.0f / 256.0f);
    float4* p = (float4*)(agg + (size_t)t * 64 + o * 8);
    p[0] = make_float4(acc[0] * sc, acc[1] * sc, acc[2] * sc, acc[3] * sc);
    p[1] = make_float4(acc[4] * sc, acc[5] * sc, acc[6] * sc, acc[7] * sc);
  }
}

// batch is sorted: per-wave register segment reduction, flush on boundary.
__global__ __launch_bounds__(256) void k_pool(const float* __restrict__ x,
                                              const float* __restrict__ b,
                                              const int* __restrict__ batch,
                                              float* __restrict__ hsum,
                                              float* __restrict__ hmax,
                                              int* __restrict__ cntg, int n) {
  int wid = (blockIdx.x * blockDim.x + threadIdx.x) >> 6;
  int lane = threadIdx.x & 63;
  int i0 = wid * 64;
  if (i0 >= n) return;
  int i1 = min(i0 + 64, n);
  float bb = b[lane];
  int batch_l = (i0 + lane < n) ? batch[i0 + lane] : 0;
  float gsum = 0.f, gmax = 0.f;
  int cur = __shfl(batch_l, 0);
  int c = 0;
  for (int i = i0; i < i1; i++) {
    int g = __shfl(batch_l, i - i0);
    if (g != cur) {
      atomicAdd(&hsum[cur * 64 + lane], gsum);
      atomicMax((int*)&hmax[cur * 64 + lane], __float_as_int(gmax));
      if (lane == 0) atomicAdd(&cntg[cur], c);
      gsum = 0.f; gmax = 0.f; c = 0; cur = g;
    }
    float v = fmaxf(x[(long)i * 64 + lane] + bb, 0.0f);
    gsum += v;
    gmax = fmaxf(gmax, v);
    c++;
  }
  atomicAdd(&hsum[cur * 64 + lane], gsum);
  atomicMax((int*)&hmax[cur * 64 + lane], __float_as_int(gmax));
  if (lane == 0) atomicAdd(&cntg[cur], c);
}

// one block (64 threads) per graph: logits = relu(h@Wc1+bc1)@Wc2+bc2
__global__ __launch_bounds__(64) void k_cls(const float* __restrict__ hsum,
                                            const float* __restrict__ hmax,
                                            const int* __restrict__ cnt,
                                            const float* __restrict__ Wc1,
                                            const float* __restrict__ bc1,
                                            const float* __restrict__ Wc2,
                                            const float* __restrict__ bc2,
                                            float* __restrict__ out) {
  __shared__ float h[128];
  __shared__ float hid[64];
  int g = blockIdx.x, j = threadIdx.x;
  int c = cnt[g];
  float cf = (float)(c > 0 ? c : 1);
  h[j] = hsum[g * 64 + j] / cf;
  h[64 + j] = hmax[g * 64 + j];
  __syncthreads();
  float acc = bc1[j];
  for (int k = 0; k < 128; k++) acc += h[k] * Wc1[k * 64 + j];
  hid[j] = fmaxf(acc, 0.f);
  __syncthreads();
  if (j < 2) {
    float a = bc2[j];
    for (int k = 0; k < 64; k++) a += hid[k] * Wc2[k * 2 + j];
    out[g * 2 + j] = a;
  }
}

extern "C" void kernel_launch(void* const* d_in, const int* in_sizes, int n_in,
                              void* d_out, int out_size, void* d_ws, size_t ws_size,
                              hipStream_t stream) {
  const int N = in_sizes[0];
  const int E = in_sizes[1] / 2;
  const int G = out_size / 2;
  const int B = (N + BKT - 1) >> BKT_LOG;

  const int* tok   = (const int*)d_in[0];
  const int* ei    = (const int*)d_in[1];
  const int* batch = (const int*)d_in[2];
  const float* emb = (const float*)d_in[3];
  const float* W0 = (const float*)d_in[4];  const float* b0 = (const float*)d_in[5];
  const float* W1 = (const float*)d_in[6];  const float* b1 = (const float*)d_in[7];
  const float* W2 = (const float*)d_in[8];  const float* b2 = (const float*)d_in[9];
  const float* Wc1 = (const float*)d_in[10]; const float* bc1 = (const float*)d_in[11];
  const float* Wc2 = (const float*)d_in[12]; const float* bc2 = (const float*)d_in[13];
  const int* srcp = ei;
  const int* dstp = ei + E;

  // ---- workspace carve-up (4-byte units) ----
  int* off    = (int*)d_ws;                      // N+2
  int* csrc   = off + N + 2;                     // E
  float* dinv = (float*)(csrc + E);              // N
  int* chist  = (int*)(dinv + N);                // 256
  int* cbase  = chist + 256;                     // 256 (B+1 used)
  int* gcur   = cbase + 256;                     // 256
  __half2* xh = (__half2*)(gcur + 256);          // N*32 half2 (12.8 MB)
  float* bufA = (float*)((int*)(gcur + 256) + (size_t)N * 32);  // N*64 fp32
  float* bufB = bufA + (size_t)N * 64;           // N*64 fp32
  int2* ebuf  = (int2*)bufA;                     // E pairs (dead before agg0)
  float* hsum = bufB + (size_t)N * 64;           // G*64
  float* hmax = hsum + (size_t)G * 64;           // G*64
  int*   cntg = (int*)(hmax + (size_t)G * 64);   // G

  auto cdiv = [](long a, long b) { return (int)((a + b - 1) / b); };

  // ---- CSR build (single-writer placement) ----
  k_zero<<<1, 256, 0, stream>>>((float*)chist, 256);
  k_chist<<<cdiv(E, CHUNK), 256, 0, stream>>>(dstp, chist, E, B);
  k_cscan<<<1, 256, 0, stream>>>(chist, cbase, gcur, E, B);
  k_part<<<cdiv(E, CHUNK), 256, 0, stream>>>(srcp, dstp, gcur, ebuf, E, B);
  k_bplace<<<B, 512, 0, stream>>>(ebuf, cbase, off, csrc, dinv, N, E);

  // ---- 3 GCN layers ----
  k_matmul<true, false><<<cdiv(N, 256), 256, 0, stream>>>(nullptr, tok, emb, W0, nullptr, dinv, xh, N);
  k_aggregate<<<cdiv(N, 32), 256, 0, stream>>>(off, csrc, dinv, xh, bufA, N);

  k_matmul<false, true><<<cdiv(N, 256), 256, 0, stream>>>(bufA, nullptr, nullptr, W1, b0, dinv, xh, N);
  k_aggregate<<<cdiv(N, 32), 256, 0, stream>>>(off, csrc, dinv, xh, bufB, N);

  k_matmul<false, true><<<cdiv(N, 256), 256, 0, stream>>>(bufB, nullptr, nullptr, W2, b1, dinv, xh, N);
  k_aggregate<<<cdiv(N, 32), 256, 0, stream>>>(off, csrc, dinv, xh, bufA, N);

  // ---- pooling (relu+b2 fused) ----
  k_zero<<<cdiv((long)G * 129, 256), 256, 0, stream>>>(hsum, (long)G * 129);
  k_pool<<<cdiv(N, 256), 256, 0, stream>>>(bufA, b2, batch, hsum, hmax, cntg, N);

  // ---- classifier head ----
  k_cls<<<G, 64, 0, stream>>>(hsum, hmax, cntg, Wc1, bc1, Wc2, bc2, (float*)d_out);
}